// Round 6
// baseline (448.346 us; speedup 1.0000x reference)
//
#include <hip/hip_runtime.h>

typedef unsigned short ushort_t;
typedef short s16x8 __attribute__((ext_vector_type(8)));
typedef float f32x4 __attribute__((ext_vector_type(4)));
typedef unsigned short u16x4 __attribute__((ext_vector_type(4)));
typedef unsigned int uint2_t __attribute__((ext_vector_type(2)));
typedef unsigned int uint4_t __attribute__((ext_vector_type(4)));

#define KDIM 256
#define BK 64
#define LDST 72          // 64 + 8 pad (bf16 elems)
#define LV_TOTAL 21760
#define NQ 8000
#define NSTRIPS 5440     // 174080 / 32 (32-row strips, one wave each, per n-half)
#define NQOA_BLOCKS 96   // 32 m-tiles (256 rows) x 3 n-tiles (128 cols)

__device__ inline unsigned short f2b(float f) {
  union { float f; unsigned u; } v; v.f = f;
  return (unsigned short)((v.u + 0x7fffu + ((v.u >> 16) & 1u)) >> 16);  // RNE
}
__device__ inline float b2f(unsigned short h) {
  union { unsigned u; float f; } v; v.u = ((unsigned)h) << 16;
  return v.f;
}
// round-half-up bf16 pair pack: 2x v_add_u32 + 1x v_perm_b32
__device__ inline unsigned pack_bf16x2(float lo, float hi) {
  union { float f; unsigned u; } a, b;
  a.f = lo; b.f = hi;
  return __builtin_amdgcn_perm(b.u + 0x8000u, a.u + 0x8000u, 0x07060302u);
}
__device__ inline unsigned short f2b_cheap(float f) {
  union { float f; unsigned u; } v; v.f = f;
  return (unsigned short)((v.u + 0x8000u) >> 16);
}

// ---- weight prep: transpose to [n][k] + bf16 convert; zero strip counters ----
__global__ __launch_bounds__(256) void prep_weights(
    const float* __restrict__ w_off, const float* __restrict__ w_attn,
    const float* __restrict__ w_val, const float* __restrict__ w_out,
    const float* __restrict__ b_off, const float* __restrict__ b_attn,
    ushort_t* __restrict__ wt_val, ushort_t* __restrict__ wt_qoa,
    ushort_t* __restrict__ wt_out, float* __restrict__ bias_qoa,
    int* __restrict__ counters)
{
  int bid = blockIdx.x;
  int k = threadIdx.x;
  if (bid < 256) {
    int n = bid;
    wt_val[n*KDIM + k] = f2b(w_val[k*256 + n]);
  } else if (bid < 640) {
    int n = bid - 256;
    float v = (n < 256) ? w_off[k*256 + n] : w_attn[k*128 + (n - 256)];
    wt_qoa[n*KDIM + k] = f2b(v);
  } else if (bid < 896) {
    int n = bid - 640;
    wt_out[n*KDIM + k] = f2b(w_out[k*256 + n]);
  } else {
    if (k < 2) counters[k] = 0;
    for (int i = k; i < 384; i += 256)
      bias_qoa[i] = (i < 256) ? b_off[i] : b_attn[i - 256];
  }
}

// ---- merged launch, 512-thread blocks. blocks [0,96) = qoa GEMM; [96,608) = vproj.
// vproj: per-WAVE atomic 32-row strip claims, zero barriers in steady state,
// cheap add+perm bf16 pack (load-issue was throttled by 4-op RNE conversions).
__global__ __launch_bounds__(512) void merged_gemms(
    const float* __restrict__ value, const ushort_t* __restrict__ wt_val,
    const float* __restrict__ b_val, ushort_t* __restrict__ v_proj,
    const float* __restrict__ query, const ushort_t* __restrict__ wt_qoa,
    const float* __restrict__ bias_qoa, float* __restrict__ qoa,
    int* __restrict__ counters)
{
  __shared__ __align__(16) char smem[65536];
  const int tid  = threadIdx.x;
  const int wave = tid >> 6;      // 0..7
  const int lane = tid & 63;
  const int lrow = lane & 15;
  const int quad = lane >> 4;

  if (blockIdx.x < NQOA_BLOCKS) {
    // ---------------- qoa GEMM path: 256-row x 128-col tiles ----------------
    ushort_t* sA = (ushort_t*)smem;                     // 256*72*2 = 36864
    ushort_t* sB = (ushort_t*)(smem + 256 * LDST * 2);  // 128*72*2 = 18432
    const int m0 = (blockIdx.x & 31) * 256;
    const int n0 = (blockIdx.x >> 5) * 128;
    const int M = NQ, N = 384;

    f32x4 acc[2][8];
    #pragma unroll
    for (int i = 0; i < 2; ++i)
      #pragma unroll
      for (int j = 0; j < 8; ++j) acc[i][j] = {0.f, 0.f, 0.f, 0.f};

    for (int kc = 0; kc < KDIM; kc += BK) {
      #pragma unroll
      for (int i = 0; i < 8; ++i) {
        int f   = tid + i * 512;
        int row = f >> 4;
        int c4  = f & 15;
        int gr  = m0 + row;
        float4 val = {0.f, 0.f, 0.f, 0.f};
        if (gr < M) val = *(const float4*)(query + (size_t)gr * KDIM + kc + c4 * 4);
        uint2_t t;
        t.x = pack_bf16x2(val.x, val.y);
        t.y = pack_bf16x2(val.z, val.w);
        *(uint2_t*)&sA[row * LDST + c4 * 4] = t;
      }
      #pragma unroll
      for (int i = 0; i < 2; ++i) {
        int g   = tid + i * 512;
        int row = g >> 3;
        int seg = g & 7;
        s16x8 v = *(const s16x8*)(wt_qoa + (size_t)(n0 + row) * KDIM + kc + seg * 8);
        *(s16x8*)&sB[row * LDST + seg * 8] = v;
      }
      __syncthreads();
      #pragma unroll
      for (int ki = 0; ki < BK; ki += 32) {
        int krow = ki + quad * 8;
        s16x8 af[2], bfr[8];
        #pragma unroll
        for (int mt = 0; mt < 2; ++mt)
          af[mt] = *(const s16x8*)&sA[(wave * 32 + mt * 16 + lrow) * LDST + krow];
        #pragma unroll
        for (int nt = 0; nt < 8; ++nt)
          bfr[nt] = *(const s16x8*)&sB[(nt * 16 + lrow) * LDST + krow];
        #pragma unroll
        for (int mt = 0; mt < 2; ++mt)
          #pragma unroll
          for (int nt = 0; nt < 8; ++nt)
            acc[mt][nt] = __builtin_amdgcn_mfma_f32_16x16x32_bf16(
                af[mt], bfr[nt], acc[mt][nt], 0, 0, 0);
      }
      __syncthreads();
    }
    #pragma unroll
    for (int mt = 0; mt < 2; ++mt) {
      int gmb = m0 + wave * 32 + mt * 16 + quad * 4;
      #pragma unroll
      for (int nt = 0; nt < 8; ++nt) {
        int gn = n0 + nt * 16 + lrow;
        float bvv = bias_qoa[gn];
        #pragma unroll
        for (int r = 0; r < 4; ++r) {
          int gm = gmb + r;
          if (gm < M) qoa[(size_t)gm * N + gn] = acc[mt][nt][r] + bvv;
        }
      }
    }
    return;
  }

  // ---------------- vproj path: persistent-B, per-wave strip claims ----------------
  ushort_t* sB = (ushort_t*)smem;   // 128*256*2 = 65536
  const int vbid = blockIdx.x - NQOA_BLOCKS;   // 0..511
  const int half = vbid & 1;
  const int n0   = half * 128;

  // stage B-half: 128 rows x 32 chunks(16B); store chunk c at (c ^ (row&7))
  {
    const ushort_t* src = wt_val + (size_t)n0 * KDIM;
    #pragma unroll
    for (int i = 0; i < 8; ++i) {
      int g   = tid + i * 512;
      int row = g >> 5;
      int c   = g & 31;
      s16x8 v = *(const s16x8*)(src + row * KDIM + c * 8);
      *(s16x8*)&sB[row * 256 + ((c ^ (row & 7)) * 8)] = v;
    }
  }
  __syncthreads();

  float bv[8];
  #pragma unroll
  for (int nt = 0; nt < 8; ++nt) bv[nt] = b_val[n0 + nt * 16 + lrow];

  const int swz = lrow & 7;

  while (true) {
    int strip;
    if (lane == 0) strip = atomicAdd(&counters[half], 1);
    strip = __shfl(strip, 0);
    if (strip >= NSTRIPS) break;
    const int m0 = strip * 32;
    const float* arow0 = value + (size_t)(m0 + lrow) * KDIM + quad * 8;
    const float* arow1 = arow0 + 16 * KDIM;

    f32x4 acc[2][8];
    #pragma unroll
    for (int m = 0; m < 2; ++m)
      #pragma unroll
      for (int nt = 0; nt < 8; ++nt) acc[m][nt] = {0.f, 0.f, 0.f, 0.f};

    float4 st[2][2][2];   // [buf][mtile][half]
    st[0][0][0] = *(const float4*)(arow0);
    st[0][0][1] = *(const float4*)(arow0 + 4);
    st[0][1][0] = *(const float4*)(arow1);
    st[0][1][1] = *(const float4*)(arow1 + 4);

    #pragma unroll
    for (int ks = 0; ks < 8; ++ks) {
      const int cur = ks & 1, nxt = cur ^ 1;
      if (ks < 7) {
        const float* p0 = arow0 + (ks + 1) * 32;
        const float* p1 = arow1 + (ks + 1) * 32;
        st[nxt][0][0] = *(const float4*)(p0);
        st[nxt][0][1] = *(const float4*)(p0 + 4);
        st[nxt][1][0] = *(const float4*)(p1);
        st[nxt][1][1] = *(const float4*)(p1 + 4);
      }
      s16x8 af[2];
      #pragma unroll
      for (int m = 0; m < 2; ++m) {
        union { uint4_t d; s16x8 v; } u;
        u.d.x = pack_bf16x2(st[cur][m][0].x, st[cur][m][0].y);
        u.d.y = pack_bf16x2(st[cur][m][0].z, st[cur][m][0].w);
        u.d.z = pack_bf16x2(st[cur][m][1].x, st[cur][m][1].y);
        u.d.w = pack_bf16x2(st[cur][m][1].z, st[cur][m][1].w);
        af[m] = u.v;
      }
      #pragma unroll
      for (int nt = 0; nt < 8; ++nt) {
        s16x8 bf = *(const s16x8*)&sB[(nt * 16 + lrow) * 256 +
                                      (((4 * ks + quad) ^ swz) * 8)];
        acc[0][nt] = __builtin_amdgcn_mfma_f32_16x16x32_bf16(af[0], bf, acc[0][nt], 0, 0, 0);
        acc[1][nt] = __builtin_amdgcn_mfma_f32_16x16x32_bf16(af[1], bf, acc[1][nt], 0, 0, 0);
      }
    }

    #pragma unroll
    for (int m = 0; m < 2; ++m) {
      int gm = m0 + m * 16 + quad * 4;
      #pragma unroll
      for (int nt = 0; nt < 8; ++nt) {
        int gn = n0 + nt * 16 + lrow;
        #pragma unroll
        for (int r = 0; r < 4; ++r)
          v_proj[(size_t)(gm + r) * KDIM + gn] = f2b_cheap(acc[m][nt][r] + bv[nt]);
      }
    }
  }
}

// ---- sampler: 16B corner loads + shfl_xor corner-class reduction ----
__global__ __launch_bounds__(256) void ms_deform_sample(
    const ushort_t* __restrict__ v,     // [BS][21760][256] bf16
    const float* __restrict__ qoa,      // [8000][384]
    const float* __restrict__ refp,     // [8000][4]
    float* __restrict__ outq)           // [8000][256]
{
  __shared__ float s_w[512];
  __shared__ int   s_i[512];
  const int bq  = blockIdx.x;
  const int b   = bq / 1000;
  const int tid = threadIdx.x;

  if (tid < 128) {
    const int p = tid & 15;
    const float* qrow = qoa + (size_t)bq * 384;
    float logit = qrow[256 + tid];
    float mx = logit;
    #pragma unroll
    for (int s = 8; s >= 1; s >>= 1) mx = fmaxf(mx, __shfl_xor(mx, s, 16));
    float e = __expf(logit - mx);
    float sum = e;
    #pragma unroll
    for (int s = 8; s >= 1; s >>= 1) sum += __shfl_xor(sum, s, 16);
    float aw = e / sum;

    float ox = qrow[tid * 2], oy = qrow[tid * 2 + 1];
    const float* rp = refp + (size_t)bq * 4;
    float rx = rp[0], ry = rp[1], rw = rp[2], rh = rp[3];
    const int lvl = p >> 2;
    const int HWs[4] = {128, 64, 32, 16};
    const int STs[4] = {0, 16384, 20480, 21504};
    int W = HWs[lvl], H = HWs[lvl], st = STs[lvl];
    float lx = rx + ox * 0.125f * rw;
    float ly = ry + oy * 0.125f * rh;
    float x = lx * (float)W - 0.5f;
    float y = ly * (float)H - 0.5f;
    float x0f = floorf(x), y0f = floorf(y);
    int x0 = (int)x0f, y0 = (int)y0f;
    float fx = x - x0f, fy = y - y0f;
    float wc[4] = {(1.f - fx) * (1.f - fy), fx * (1.f - fy),
                   (1.f - fx) * fy,         fx * fy};
    #pragma unroll
    for (int c = 0; c < 4; ++c) {
      int xi = x0 + (c & 1);
      int yi = y0 + (c >> 1);
      bool valid = (xi >= 0) && (xi < W) && (yi >= 0) && (yi < H);
      int xc = min(max(xi, 0), W - 1);
      int yc = min(max(yi, 0), H - 1);
      s_w[tid * 4 + c] = valid ? wc[c] * aw : 0.f;
      s_i[tid * 4 + c] = st + yc * W + xc;
    }
  }
  __syncthreads();

  const int h   = tid >> 5;
  const int l32 = tid & 31;
  const int grp = l32 >> 2;        // corner class 0..7
  const int sub = l32 & 3;         // dim octet 0..3
  const ushort_t* vb = v + (size_t)b * LV_TOTAL * 256 + h * 32 + sub * 8;

  float acc[8];
  #pragma unroll
  for (int d = 0; d < 8; ++d) acc[d] = 0.f;

  #pragma unroll
  for (int i = 0; i < 8; ++i) {
    int j = i * 8 + grp;
    float w  = s_w[h * 64 + j];
    int  idx = s_i[h * 64 + j];
    s16x8 vv = *(const s16x8*)(vb + (size_t)idx * 256);
    #pragma unroll
    for (int d = 0; d < 8; ++d)
      acc[d] += w * b2f((ushort_t)vv[d]);
  }
  #pragma unroll
  for (int m = 4; m <= 16; m <<= 1)
    #pragma unroll
    for (int d = 0; d < 8; ++d)
      acc[d] += __shfl_xor(acc[d], m);

  if (l32 < 4) {
    float* dst = outq + (size_t)bq * 256 + h * 32 + l32 * 8;
    float4 o0 = {acc[0], acc[1], acc[2], acc[3]};
    float4 o1 = {acc[4], acc[5], acc[6], acc[7]};
    *(float4*)dst = o0;
    *(float4*)(dst + 4) = o1;
  }
}

// ---- generic MFMA GEMM (final out-projection) ----
__global__ __launch_bounds__(256) void gemm_bf16(
    const float* __restrict__ A, const ushort_t* __restrict__ Bt,
    const float* __restrict__ bias, float* __restrict__ Cf,
    int M, int N)
{
  __shared__ ushort_t sA[128 * LDST];
  __shared__ ushort_t sB[128 * LDST];
  const int tid  = threadIdx.x;
  const int m0   = blockIdx.x * 128;
  const int n0   = blockIdx.y * 128;
  const int wave = tid >> 6;
  const int lane = tid & 63;
  const int lrow = lane & 15;
  const int quad = lane >> 4;

  f32x4 acc[2][8];
  #pragma unroll
  for (int i = 0; i < 2; ++i)
    #pragma unroll
    for (int j = 0; j < 8; ++j) acc[i][j] = {0.f, 0.f, 0.f, 0.f};

  for (int kc = 0; kc < KDIM; kc += BK) {
    #pragma unroll
    for (int i = 0; i < 8; ++i) {
      int f   = tid + i * 256;
      int row = f >> 4;
      int c4  = f & 15;
      int gr  = m0 + row;
      float4 val = {0.f, 0.f, 0.f, 0.f};
      if (gr < M) val = *(const float4*)(A + (size_t)gr * KDIM + kc + c4 * 4);
      uint2_t t;
      t.x = pack_bf16x2(val.x, val.y);
      t.y = pack_bf16x2(val.z, val.w);
      *(uint2_t*)&sA[row * LDST + c4 * 4] = t;
    }
    #pragma unroll
    for (int i = 0; i < 4; ++i) {
      int f   = tid + i * 256;
      int row = f >> 3;
      int seg = f & 7;
      s16x8 v = *(const s16x8*)(Bt + (size_t)(n0 + row) * KDIM + kc + seg * 8);
      *(s16x8*)&sB[row * LDST + seg * 8] = v;
    }
    __syncthreads();
    #pragma unroll
    for (int ki = 0; ki < BK; ki += 32) {
      int krow = ki + quad * 8;
      s16x8 af[2], bfr[8];
      #pragma unroll
      for (int mt = 0; mt < 2; ++mt)
        af[mt] = *(const s16x8*)&sA[(wave * 32 + mt * 16 + lrow) * LDST + krow];
      #pragma unroll
      for (int nt = 0; nt < 8; ++nt)
        bfr[nt] = *(const s16x8*)&sB[(nt * 16 + lrow) * LDST + krow];
      #pragma unroll
      for (int mt = 0; mt < 2; ++mt)
        #pragma unroll
        for (int nt = 0; nt < 8; ++nt)
          acc[mt][nt] = __builtin_amdgcn_mfma_f32_16x16x32_bf16(
              af[mt], bfr[nt], acc[mt][nt], 0, 0, 0);
    }
    __syncthreads();
  }
  #pragma unroll
  for (int mt = 0; mt < 2; ++mt) {
    int gmb = m0 + wave * 32 + mt * 16 + quad * 4;
    #pragma unroll
    for (int nt = 0; nt < 8; ++nt) {
      int gn = n0 + nt * 16 + lrow;
      float bvv = bias[gn];
      #pragma unroll
      for (int r = 0; r < 4; ++r) {
        int gm = gmb + r;
        if (gm < M) Cf[(size_t)gm * N + gn] = acc[mt][nt][r] + bvv;
      }
    }
  }
}

extern "C" void kernel_launch(void* const* d_in, const int* in_sizes, int n_in,
                              void* d_out, int out_size, void* d_ws, size_t ws_size,
                              hipStream_t stream) {
  const float* query  = (const float*)d_in[0];
  const float* refp   = (const float*)d_in[1];
  const float* value  = (const float*)d_in[2];
  const float* w_off  = (const float*)d_in[4];
  const float* b_off  = (const float*)d_in[5];
  const float* w_attn = (const float*)d_in[6];
  const float* b_attn = (const float*)d_in[7];
  const float* w_val  = (const float*)d_in[8];
  const float* b_val  = (const float*)d_in[9];
  const float* w_out  = (const float*)d_in[10];
  const float* b_out  = (const float*)d_in[11];
  float* out = (float*)d_out;

  char* ws = (char*)d_ws;
  const size_t WS_NEEDED = 110069760;
  if (ws_size < WS_NEEDED) return;
  ushort_t* wt_val   = (ushort_t*)(ws);                 // 131072
  ushort_t* wt_qoa   = (ushort_t*)(ws + 131072);        // 196608
  ushort_t* wt_out   = (ushort_t*)(ws + 327680);        // 131072
  float*    bias_qoa = (float*)   (ws + 458752);        // 1536
  int*      counters = (int*)     (ws + 460288);        // 512 (2 used)
  ushort_t* v_proj   = (ushort_t*)(ws + 460800);        // 89128960
  float*    qoa      = (float*)   (ws + 89589760);      // 12288000
  float*    outq     = (float*)   (ws + 101877760);     // 8192000

  prep_weights<<<897, 256, 0, stream>>>(w_off, w_attn, w_val, w_out, b_off, b_attn,
                                        wt_val, wt_qoa, wt_out, bias_qoa, counters);
  // qoa GEMM (blocks 0..95) + value projection (blocks 96..607), 512-thr blocks
  merged_gemms<<<NQOA_BLOCKS + 512, 512, 0, stream>>>(
      value, wt_val, b_val, v_proj, query, wt_qoa, bias_qoa, qoa, counters);
  // sampling + softmax + weighted sum
  ms_deform_sample<<<NQ, 256, 0, stream>>>(v_proj, qoa, refp, outq);
  // output projection
  gemm_bf16<<<dim3(63, 2), 256, 0, stream>>>(outq, wt_out, b_out, out, NQ, 256);
}

// Round 7
// 363.126 us; speedup vs baseline: 1.2347x; 1.2347x over previous
//
#include <hip/hip_runtime.h>

typedef unsigned short ushort_t;
typedef short s16x8 __attribute__((ext_vector_type(8)));
typedef float f32x4 __attribute__((ext_vector_type(4)));
typedef unsigned short u16x4 __attribute__((ext_vector_type(4)));
typedef unsigned int uint2_t __attribute__((ext_vector_type(2)));
typedef unsigned int uint4_t __attribute__((ext_vector_type(4)));

#define KDIM 256
#define BK 64
#define LDST 72          // 64 + 8 pad (bf16 elems)
#define LV_TOTAL 21760
#define NQ 8000
#define VM_TILES 1360    // 174080 / 128 (128-row tiles, block-claimed)
#define NQOA_BLOCKS 189  // 63 m-tiles (128 rows) x 3 n-tiles (128 cols)

__device__ inline unsigned short f2b(float f) {
  union { float f; unsigned u; } v; v.f = f;
  return (unsigned short)((v.u + 0x7fffu + ((v.u >> 16) & 1u)) >> 16);  // RNE
}
__device__ inline float b2f(unsigned short h) {
  union { unsigned u; float f; } v; v.u = ((unsigned)h) << 16;
  return v.f;
}
// round-half-up bf16 pair pack: 2x v_add_u32 + 1x v_perm_b32
__device__ inline unsigned pack_bf16x2(float lo, float hi) {
  union { float f; unsigned u; } a, b;
  a.f = lo; b.f = hi;
  return __builtin_amdgcn_perm(b.u + 0x8000u, a.u + 0x8000u, 0x07060302u);
}
__device__ inline unsigned short f2b_cheap(float f) {
  union { float f; unsigned u; } v; v.f = f;
  return (unsigned short)((v.u + 0x8000u) >> 16);
}

// ---- weight prep: transpose to [n][k] + bf16 convert; zero tile counters ----
__global__ __launch_bounds__(256) void prep_weights(
    const float* __restrict__ w_off, const float* __restrict__ w_attn,
    const float* __restrict__ w_val, const float* __restrict__ w_out,
    const float* __restrict__ b_off, const float* __restrict__ b_attn,
    ushort_t* __restrict__ wt_val, ushort_t* __restrict__ wt_qoa,
    ushort_t* __restrict__ wt_out, float* __restrict__ bias_qoa,
    int* __restrict__ counters)
{
  int bid = blockIdx.x;
  int k = threadIdx.x;
  if (bid < 256) {
    int n = bid;
    wt_val[n*KDIM + k] = f2b(w_val[k*256 + n]);
  } else if (bid < 640) {
    int n = bid - 256;
    float v = (n < 256) ? w_off[k*256 + n] : w_attn[k*128 + (n - 256)];
    wt_qoa[n*KDIM + k] = f2b(v);
  } else if (bid < 896) {
    int n = bid - 640;
    wt_out[n*KDIM + k] = f2b(w_out[k*256 + n]);
  } else {
    if (k < 2) counters[k] = 0;
    for (int i = k; i < 384; i += 256)
      bias_qoa[i] = (i < 256) ? b_off[i] : b_attn[i - 256];
  }
}

// ---- merged launch (R4 structure restored): 256-thread blocks.
// blocks [0,189) = qoa GEMM (128x128 tiles); [189,701) = vproj persistent-B,
// block-level atomic 128-row tile claims. Cheap add+perm bf16 pack.
__global__ __launch_bounds__(256) void merged_gemms(
    const float* __restrict__ value, const ushort_t* __restrict__ wt_val,
    const float* __restrict__ b_val, ushort_t* __restrict__ v_proj,
    const float* __restrict__ query, const ushort_t* __restrict__ wt_qoa,
    const float* __restrict__ bias_qoa, float* __restrict__ qoa,
    int* __restrict__ counters)
{
  __shared__ __align__(16) char smem[65536];
  __shared__ int s_mt;
  const int tid  = threadIdx.x;
  const int wave = tid >> 6;
  const int lane = tid & 63;
  const int lrow = lane & 15;
  const int quad = lane >> 4;

  if (blockIdx.x < NQOA_BLOCKS) {
    // ---------------- qoa GEMM path ----------------
    ushort_t* sA = (ushort_t*)smem;                 // 128*72*2 = 18432
    ushort_t* sB = (ushort_t*)(smem + 128 * LDST * 2);
    const int m0 = (blockIdx.x % 63) * 128;
    const int n0 = (blockIdx.x / 63) * 128;
    const int M = NQ, N = 384;

    f32x4 acc[2][8];
    #pragma unroll
    for (int i = 0; i < 2; ++i)
      #pragma unroll
      for (int j = 0; j < 8; ++j) acc[i][j] = {0.f, 0.f, 0.f, 0.f};

    for (int kc = 0; kc < KDIM; kc += BK) {
      #pragma unroll
      for (int i = 0; i < 8; ++i) {
        int f   = tid + i * 256;
        int row = f >> 4;
        int c4  = f & 15;
        int gr  = m0 + row;
        float4 val = {0.f, 0.f, 0.f, 0.f};
        if (gr < M) val = *(const float4*)(query + (size_t)gr * KDIM + kc + c4 * 4);
        uint2_t t;
        t.x = pack_bf16x2(val.x, val.y);
        t.y = pack_bf16x2(val.z, val.w);
        *(uint2_t*)&sA[row * LDST + c4 * 4] = t;
      }
      #pragma unroll
      for (int i = 0; i < 4; ++i) {
        int f   = tid + i * 256;
        int row = f >> 3;
        int seg = f & 7;
        s16x8 v = *(const s16x8*)(wt_qoa + (size_t)(n0 + row) * KDIM + kc + seg * 8);
        *(s16x8*)&sB[row * LDST + seg * 8] = v;
      }
      __syncthreads();
      #pragma unroll
      for (int ki = 0; ki < BK; ki += 32) {
        int krow = ki + quad * 8;
        s16x8 af[2], bfr[8];
        #pragma unroll
        for (int mt = 0; mt < 2; ++mt)
          af[mt] = *(const s16x8*)&sA[(wave * 32 + mt * 16 + lrow) * LDST + krow];
        #pragma unroll
        for (int nt = 0; nt < 8; ++nt)
          bfr[nt] = *(const s16x8*)&sB[(nt * 16 + lrow) * LDST + krow];
        #pragma unroll
        for (int mt = 0; mt < 2; ++mt)
          #pragma unroll
          for (int nt = 0; nt < 8; ++nt)
            acc[mt][nt] = __builtin_amdgcn_mfma_f32_16x16x32_bf16(
                af[mt], bfr[nt], acc[mt][nt], 0, 0, 0);
      }
      __syncthreads();
    }
    #pragma unroll
    for (int mt = 0; mt < 2; ++mt) {
      int gmb = m0 + wave * 32 + mt * 16 + quad * 4;
      #pragma unroll
      for (int nt = 0; nt < 8; ++nt) {
        int gn = n0 + nt * 16 + lrow;
        float bvv = bias_qoa[gn];
        #pragma unroll
        for (int r = 0; r < 4; ++r) {
          int gm = gmb + r;
          if (gm < M) qoa[(size_t)gm * N + gn] = acc[mt][nt][r] + bvv;
        }
      }
    }
    return;
  }

  // ---------------- vproj path: persistent-B, block-level tile claims ----------------
  ushort_t* sB = (ushort_t*)smem;   // 128*256*2 = 65536
  const int vbid = blockIdx.x - NQOA_BLOCKS;   // 0..511
  const int half = vbid & 1;
  const int n0   = half * 128;

  // stage B-half: 128 rows x 32 chunks(16B); store chunk c at (c ^ (row&7))
  {
    const ushort_t* src = wt_val + (size_t)n0 * KDIM;
    #pragma unroll
    for (int i = 0; i < 16; ++i) {
      int g   = tid + i * 256;
      int row = g >> 5;
      int c   = g & 31;
      s16x8 v = *(const s16x8*)(src + row * KDIM + c * 8);
      *(s16x8*)&sB[row * 256 + ((c ^ (row & 7)) * 8)] = v;
    }
  }
  __syncthreads();

  float bv[8];
  #pragma unroll
  for (int nt = 0; nt < 8; ++nt) bv[nt] = b_val[n0 + nt * 16 + lrow];

  const int swz = lrow & 7;

  while (true) {
    if (tid == 0) s_mt = atomicAdd(&counters[half], 1);
    __syncthreads();
    const int mt = s_mt;
    if (mt >= VM_TILES) break;
    const int m0 = mt * 128;
    const float* arow0 = value + (size_t)(m0 + wave * 32 + lrow) * KDIM + quad * 8;
    const float* arow1 = arow0 + 16 * KDIM;

    f32x4 acc[2][8];
    #pragma unroll
    for (int m = 0; m < 2; ++m)
      #pragma unroll
      for (int nt = 0; nt < 8; ++nt) acc[m][nt] = {0.f, 0.f, 0.f, 0.f};

    float4 st[2][2][2];   // [buf][mtile][half]
    st[0][0][0] = *(const float4*)(arow0);
    st[0][0][1] = *(const float4*)(arow0 + 4);
    st[0][1][0] = *(const float4*)(arow1);
    st[0][1][1] = *(const float4*)(arow1 + 4);

    #pragma unroll
    for (int ks = 0; ks < 8; ++ks) {
      const int cur = ks & 1, nxt = cur ^ 1;
      if (ks < 7) {
        const float* p0 = arow0 + (ks + 1) * 32;
        const float* p1 = arow1 + (ks + 1) * 32;
        st[nxt][0][0] = *(const float4*)(p0);
        st[nxt][0][1] = *(const float4*)(p0 + 4);
        st[nxt][1][0] = *(const float4*)(p1);
        st[nxt][1][1] = *(const float4*)(p1 + 4);
      }
      s16x8 af[2];
      #pragma unroll
      for (int m = 0; m < 2; ++m) {
        union { uint4_t d; s16x8 v; } u;
        u.d.x = pack_bf16x2(st[cur][m][0].x, st[cur][m][0].y);
        u.d.y = pack_bf16x2(st[cur][m][0].z, st[cur][m][0].w);
        u.d.z = pack_bf16x2(st[cur][m][1].x, st[cur][m][1].y);
        u.d.w = pack_bf16x2(st[cur][m][1].z, st[cur][m][1].w);
        af[m] = u.v;
      }
      #pragma unroll
      for (int nt = 0; nt < 8; ++nt) {
        s16x8 bf = *(const s16x8*)&sB[(nt * 16 + lrow) * 256 +
                                      (((4 * ks + quad) ^ swz) * 8)];
        acc[0][nt] = __builtin_amdgcn_mfma_f32_16x16x32_bf16(af[0], bf, acc[0][nt], 0, 0, 0);
        acc[1][nt] = __builtin_amdgcn_mfma_f32_16x16x32_bf16(af[1], bf, acc[1][nt], 0, 0, 0);
      }
    }

    #pragma unroll
    for (int m = 0; m < 2; ++m) {
      int gm = m0 + wave * 32 + m * 16 + quad * 4;
      #pragma unroll
      for (int nt = 0; nt < 8; ++nt) {
        int gn = n0 + nt * 16 + lrow;
        #pragma unroll
        for (int r = 0; r < 4; ++r)
          v_proj[(size_t)(gm + r) * KDIM + gn] = f2b_cheap(acc[m][nt][r] + bv[nt]);
      }
    }
    __syncthreads();   // protect s_mt before next claim
  }
}

// ---- sampler: hoisted (w,idx) + all-8 gathers in flight, then FMA chain ----
__global__ __launch_bounds__(256) void ms_deform_sample(
    const ushort_t* __restrict__ v,     // [BS][21760][256] bf16
    const float* __restrict__ qoa,      // [8000][384]
    const float* __restrict__ refp,     // [8000][4]
    float* __restrict__ outq)           // [8000][256]
{
  __shared__ float s_w[512];
  __shared__ int   s_i[512];
  const int bq  = blockIdx.x;
  const int b   = bq / 1000;
  const int tid = threadIdx.x;

  if (tid < 128) {
    const int p = tid & 15;
    const float* qrow = qoa + (size_t)bq * 384;
    float logit = qrow[256 + tid];
    float mx = logit;
    #pragma unroll
    for (int s = 8; s >= 1; s >>= 1) mx = fmaxf(mx, __shfl_xor(mx, s, 16));
    float e = __expf(logit - mx);
    float sum = e;
    #pragma unroll
    for (int s = 8; s >= 1; s >>= 1) sum += __shfl_xor(sum, s, 16);
    float aw = e / sum;

    float ox = qrow[tid * 2], oy = qrow[tid * 2 + 1];
    const float* rp = refp + (size_t)bq * 4;
    float rx = rp[0], ry = rp[1], rw = rp[2], rh = rp[3];
    const int lvl = p >> 2;
    const int HWs[4] = {128, 64, 32, 16};
    const int STs[4] = {0, 16384, 20480, 21504};
    int W = HWs[lvl], H = HWs[lvl], st = STs[lvl];
    float lx = rx + ox * 0.125f * rw;
    float ly = ry + oy * 0.125f * rh;
    float x = lx * (float)W - 0.5f;
    float y = ly * (float)H - 0.5f;
    float x0f = floorf(x), y0f = floorf(y);
    int x0 = (int)x0f, y0 = (int)y0f;
    float fx = x - x0f, fy = y - y0f;
    float wc[4] = {(1.f - fx) * (1.f - fy), fx * (1.f - fy),
                   (1.f - fx) * fy,         fx * fy};
    #pragma unroll
    for (int c = 0; c < 4; ++c) {
      int xi = x0 + (c & 1);
      int yi = y0 + (c >> 1);
      bool valid = (xi >= 0) && (xi < W) && (yi >= 0) && (yi < H);
      int xc = min(max(xi, 0), W - 1);
      int yc = min(max(yi, 0), H - 1);
      s_w[tid * 4 + c] = valid ? wc[c] * aw : 0.f;
      s_i[tid * 4 + c] = st + yc * W + xc;
    }
  }
  __syncthreads();

  const int h   = tid >> 5;
  const int l32 = tid & 31;
  const int grp = l32 >> 2;        // corner class 0..7
  const int sub = l32 & 3;         // dim octet 0..3
  const ushort_t* vb = v + (size_t)b * LV_TOTAL * 256 + h * 32 + sub * 8;

  // hoist all weights/indices, then issue all 8 gathers back-to-back
  float wreg[8]; int ireg[8];
  #pragma unroll
  for (int i = 0; i < 8; ++i) {
    int j = h * 64 + i * 8 + grp;
    wreg[i] = s_w[j];
    ireg[i] = s_i[j];
  }
  s16x8 vv[8];
  #pragma unroll
  for (int i = 0; i < 8; ++i)
    vv[i] = *(const s16x8*)(vb + (size_t)ireg[i] * 256);

  float acc[8];
  #pragma unroll
  for (int d = 0; d < 8; ++d) acc[d] = 0.f;
  #pragma unroll
  for (int i = 0; i < 8; ++i)
    #pragma unroll
    for (int d = 0; d < 8; ++d)
      acc[d] += wreg[i] * b2f((ushort_t)vv[i][d]);

  #pragma unroll
  for (int m = 4; m <= 16; m <<= 1)
    #pragma unroll
    for (int d = 0; d < 8; ++d)
      acc[d] += __shfl_xor(acc[d], m);

  if (l32 < 4) {
    float* dst = outq + (size_t)bq * 256 + h * 32 + l32 * 8;
    float4 o0 = {acc[0], acc[1], acc[2], acc[3]};
    float4 o1 = {acc[4], acc[5], acc[6], acc[7]};
    *(float4*)dst = o0;
    *(float4*)(dst + 4) = o1;
  }
}

// ---- generic MFMA GEMM (final out-projection) ----
__global__ __launch_bounds__(256) void gemm_bf16(
    const float* __restrict__ A, const ushort_t* __restrict__ Bt,
    const float* __restrict__ bias, float* __restrict__ Cf,
    int M, int N)
{
  __shared__ ushort_t sA[128 * LDST];
  __shared__ ushort_t sB[128 * LDST];
  const int tid  = threadIdx.x;
  const int m0   = blockIdx.x * 128;
  const int n0   = blockIdx.y * 128;
  const int wave = tid >> 6;
  const int lane = tid & 63;
  const int lrow = lane & 15;
  const int quad = lane >> 4;

  f32x4 acc[2][8];
  #pragma unroll
  for (int i = 0; i < 2; ++i)
    #pragma unroll
    for (int j = 0; j < 8; ++j) acc[i][j] = {0.f, 0.f, 0.f, 0.f};

  for (int kc = 0; kc < KDIM; kc += BK) {
    #pragma unroll
    for (int i = 0; i < 8; ++i) {
      int f   = tid + i * 256;
      int row = f >> 4;
      int c4  = f & 15;
      int gr  = m0 + row;
      float4 val = {0.f, 0.f, 0.f, 0.f};
      if (gr < M) val = *(const float4*)(A + (size_t)gr * KDIM + kc + c4 * 4);
      uint2_t t;
      t.x = pack_bf16x2(val.x, val.y);
      t.y = pack_bf16x2(val.z, val.w);
      *(uint2_t*)&sA[row * LDST + c4 * 4] = t;
    }
    #pragma unroll
    for (int i = 0; i < 4; ++i) {
      int f   = tid + i * 256;
      int row = f >> 3;
      int seg = f & 7;
      s16x8 v = *(const s16x8*)(Bt + (size_t)(n0 + row) * KDIM + kc + seg * 8);
      *(s16x8*)&sB[row * LDST + seg * 8] = v;
    }
    __syncthreads();
    #pragma unroll
    for (int ki = 0; ki < BK; ki += 32) {
      int krow = ki + quad * 8;
      s16x8 af[2], bfr[8];
      #pragma unroll
      for (int mt = 0; mt < 2; ++mt)
        af[mt] = *(const s16x8*)&sA[(wave * 32 + mt * 16 + lrow) * LDST + krow];
      #pragma unroll
      for (int nt = 0; nt < 8; ++nt)
        bfr[nt] = *(const s16x8*)&sB[(nt * 16 + lrow) * LDST + krow];
      #pragma unroll
      for (int mt = 0; mt < 2; ++mt)
        #pragma unroll
        for (int nt = 0; nt < 8; ++nt)
          acc[mt][nt] = __builtin_amdgcn_mfma_f32_16x16x32_bf16(
              af[mt], bfr[nt], acc[mt][nt], 0, 0, 0);
    }
    __syncthreads();
  }
  #pragma unroll
  for (int mt = 0; mt < 2; ++mt) {
    int gmb = m0 + wave * 32 + mt * 16 + quad * 4;
    #pragma unroll
    for (int nt = 0; nt < 8; ++nt) {
      int gn = n0 + nt * 16 + lrow;
      float bvv = bias[gn];
      #pragma unroll
      for (int r = 0; r < 4; ++r) {
        int gm = gmb + r;
        if (gm < M) Cf[(size_t)gm * N + gn] = acc[mt][nt][r] + bvv;
      }
    }
  }
}

extern "C" void kernel_launch(void* const* d_in, const int* in_sizes, int n_in,
                              void* d_out, int out_size, void* d_ws, size_t ws_size,
                              hipStream_t stream) {
  const float* query  = (const float*)d_in[0];
  const float* refp   = (const float*)d_in[1];
  const float* value  = (const float*)d_in[2];
  const float* w_off  = (const float*)d_in[4];
  const float* b_off  = (const float*)d_in[5];
  const float* w_attn = (const float*)d_in[6];
  const float* b_attn = (const float*)d_in[7];
  const float* w_val  = (const float*)d_in[8];
  const float* b_val  = (const float*)d_in[9];
  const float* w_out  = (const float*)d_in[10];
  const float* b_out  = (const float*)d_in[11];
  float* out = (float*)d_out;

  char* ws = (char*)d_ws;
  const size_t WS_NEEDED = 110069760;
  if (ws_size < WS_NEEDED) return;
  ushort_t* wt_val   = (ushort_t*)(ws);                 // 131072
  ushort_t* wt_qoa   = (ushort_t*)(ws + 131072);        // 196608
  ushort_t* wt_out   = (ushort_t*)(ws + 327680);        // 131072
  float*    bias_qoa = (float*)   (ws + 458752);        // 1536
  int*      counters = (int*)     (ws + 460288);        // 512 (2 used)
  ushort_t* v_proj   = (ushort_t*)(ws + 460800);        // 89128960
  float*    qoa      = (float*)   (ws + 89589760);      // 12288000
  float*    outq     = (float*)   (ws + 101877760);     // 8192000

  prep_weights<<<897, 256, 0, stream>>>(w_off, w_attn, w_val, w_out, b_off, b_attn,
                                        wt_val, wt_qoa, wt_out, bias_qoa, counters);
  // qoa GEMM (blocks 0..188) + value projection (blocks 189..700), 256-thr blocks
  merged_gemms<<<NQOA_BLOCKS + 512, 256, 0, stream>>>(
      value, wt_val, b_val, v_proj, query, wt_qoa, bias_qoa, qoa, counters);
  // sampling + softmax + weighted sum
  ms_deform_sample<<<NQ, 256, 0, stream>>>(v_proj, qoa, refp, outq);
  // output projection
  gemm_bf16<<<dim3(63, 2), 256, 0, stream>>>(outq, wt_out, b_out, out, NQ, 256);
}